// Round 10
// baseline (461.998 us; speedup 1.0000x reference)
//
#include <hip/hip_runtime.h>
#include <hip/hip_bf16.h>

// ---------------------------------------------------------------------------
// QLenet forward, exact-math strategy (round-0 notes):
//   All fq() outputs are e5m2 grid values (<=3 significant bits). Products of
//   two grid values have <=6-bit mantissas; dot sums (<=400 terms, bounded
//   exponent span) are EXACT in f64 -> order-independent -> matches float64
//   numpy reference. Intermediates stored as bf16 (exact for grid values);
//   LDS tiles hold f32 (also exact), accumulation stays f64.
// Round 9 -> 10 (occupancy round):
//   * Both convs showed latency-bound signature (VALUBusy ~50%, Occ ~21%).
//     kconv2: 2 img/block, 1x10-row tasks (320 tasks = 320 thr exactly),
//     LDS 28.7->19.3KB. kconv1: 2 img/block, 1x7 tasks, acc7+xv11 -> ~55
//     VGPR (was 104, capping 4 waves/SIMD). More/smaller blocks -> more
//     resident waves to hide f64-FMA latency.
//   * fc2+fc3 fused (fc2 result stays in LDS); a2 round-trip deleted.
// ---------------------------------------------------------------------------

#define BATCH 8192

// fq: round to FP(e5m2) nearest-even, subnormal granule 2^-16, clip +-57344.
__device__ __forceinline__ double fq_d(double x) {
    long long b = __double_as_longlong(x);
    long long ab = b & 0x7fffffffffffffffLL;
    if (ab == 0) return x;                       // +-0 preserved
    double q;
    if (ab >= 0x3F10000000000000LL) {            // |x| >= 2^-14
        long long r = b + 0x0001FFFFFFFFFFFFLL + ((b >> 50) & 1LL);
        r &= 0xFFFC000000000000LL;
        q = __longlong_as_double(r);
        q = fmin(fmax(q, -57344.0), 57344.0);
    } else {                                     // subnormal grid: 2^-16
        q = rint(x * 65536.0) * 1.52587890625e-05;
    }
    return q;
}

__device__ __forceinline__ unsigned short bfbits(double q) {
    __hip_bfloat16 h = __float2bfloat16((float)q);
    return *(unsigned short*)&h;
}

// ---------------- merged prep ----------------
__global__ void kprep(const float* __restrict__ w1, const float* __restrict__ w2,
                      const float* __restrict__ fb1, const float* __restrict__ fb2,
                      const float* __restrict__ fb3, const float* __restrict__ fw1,
                      const float* __restrict__ fw2, const float* __restrict__ fw3,
                      float* __restrict__ qw1, float* __restrict__ qw2,
                      float* __restrict__ qfb1, float* __restrict__ qfb2,
                      float* __restrict__ qfb3, float* __restrict__ Wt1,
                      float* __restrict__ Wt2, float* __restrict__ Wt3) {
    int i = blockIdx.x * 256 + threadIdx.x;
    if (i < 150) { qw1[i] = (float)fq_d((double)w1[i]); return; }
    i -= 150;
    if (i < 2400) { qw2[i] = (float)fq_d((double)w2[i]); return; }
    i -= 2400;
    if (i < 120) { qfb1[i] = (float)fq_d((double)fb1[i]); return; }
    i -= 120;
    if (i < 84) { qfb2[i] = (float)fq_d((double)fb2[i]); return; }
    i -= 84;
    if (i < 10) { qfb3[i] = (float)fq_d((double)fb3[i]); return; }
    i -= 10;
    if (i < 51200) { int k = i / 128, o = i % 128;
        Wt1[i] = (o < 120) ? (float)fq_d((double)fw1[o * 400 + k]) : 0.0f; return; }
    i -= 51200;
    if (i < 15360) { int k = i / 128, o = i % 128;
        Wt2[i] = (o < 84) ? (float)fq_d((double)fw2[o * 120 + k]) : 0.0f; return; }
    i -= 15360;
    if (i < 1344) { int k = i / 16, o = i % 16;
        Wt3[i] = (o < 10) ? (float)fq_d((double)fw3[o * 84 + k]) : 0.0f; return; }
}
#define PREP_TOTAL (150 + 2400 + 120 + 84 + 10 + 51200 + 15360 + 1344)

// ---------------- conv1 + fq + fused BN stats ----------------
// [B,1,32,32] -> [B,6,28,28]. 2 images/block, 256 thr; task = 1x7 chunk.
// 1344 tasks (2 img x 6 co x 28 rows x 4 chunks) -> 5.25 rounds.
__global__ __launch_bounds__(256) void kconv1(const float* __restrict__ x,
        const float* __restrict__ qw, __hip_bfloat16* __restrict__ c1,
        double* __restrict__ st1) {
    __shared__ float sxf[2 * 1056];   // 2 x (32 rows x 33) f32
    __shared__ double swd[152];
    __shared__ double sred[6][2];
    int t = threadIdx.x;
    int b0 = blockIdx.x * 2;
    for (int i = t; i < 2048; i += 256) {
        int img = i >> 10, idx = i & 1023;
        sxf[img * 1056 + (idx >> 5) * 33 + (idx & 31)] =
            (float)fq_d((double)x[(size_t)(b0 + img) * 1024 + idx]);
    }
    if (t < 150) swd[t] = (double)qw[t];
    if (t >= 192 && t < 204) ((double*)sred)[t - 192] = 0.0;
    __syncthreads();
    for (int task = t; task < 1344; task += 256) {
        int img = task / 672; int rr = task % 672;
        int co = rr / 112; int rem = rr % 112;
        int i0 = rem >> 2;            // 0..27
        int j0 = (rem & 3) * 7;       // 0,7,14,21
        const float* xb = &sxf[img * 1056];
        const double* wp = &swd[co * 25];
        double acc[7];
        #pragma unroll
        for (int j = 0; j < 7; ++j) acc[j] = 0.0;
        #pragma unroll
        for (int u = 0; u < 5; ++u) {
            const float* xr = &xb[(i0 + u) * 33 + j0];
            double xv[11];
            #pragma unroll
            for (int k = 0; k < 11; ++k) xv[k] = (double)xr[k];
            double w0 = wp[u*5], w1 = wp[u*5+1], w2 = wp[u*5+2], w3 = wp[u*5+3], w4 = wp[u*5+4];
            #pragma unroll
            for (int j = 0; j < 7; ++j)
                acc[j] = fma(xv[j], w0, fma(xv[j+1], w1, fma(xv[j+2], w2,
                         fma(xv[j+3], w3, fma(xv[j+4], w4, acc[j])))));
        }
        size_t base = ((size_t)(b0 + img) * 6 + co) * 784 + (size_t)i0 * 28 + j0;
        double s = 0.0, s2 = 0.0;
        #pragma unroll
        for (int j = 0; j < 7; ++j) {
            double q = fq_d(acc[j]);
            ((unsigned short*)c1)[base + j] = bfbits(q);
            s += q; s2 += q * q;
        }
        atomicAdd(&sred[co][0], s);
        atomicAdd(&sred[co][1], s2);
    }
    __syncthreads();
    if (t < 12) atomicAdd(&st1[t * 32 + (blockIdx.x & 31)], ((double*)sred)[t]);
}

// ---------------- finalize BN from 32-binned stats ----------------
__global__ void kfinal(const double* __restrict__ st, double* __restrict__ mr,
                       int C, double N) {
    int c = threadIdx.x;
    if (c < C) {
        double s = 0.0, s2 = 0.0;
        for (int b = 0; b < 32; ++b) { s += st[c * 64 + b]; s2 += st[c * 64 + 32 + b]; }
        double m = s / N;
        double v = s2 / N - m * m;
        mr[2 * c] = m;
        mr[2 * c + 1] = 1.0 / sqrt(v + 1e-5);
    }
}

// ---------------- bn1 + fq + relu + 2x2 pool (monotone single-fq) ----------
__global__ __launch_bounds__(256) void kpool1(const __hip_bfloat16* __restrict__ c1,
        const double* __restrict__ mr1, const float* __restrict__ g1,
        const float* __restrict__ be1, __hip_bfloat16* __restrict__ p1) {
    int idx = blockIdx.x * 256 + threadIdx.x;   // pair-task: B*6*14*7
    int pp = idx % 7;  int t1 = idx / 7;
    int ph = t1 % 14;  int t2 = t1 / 14;
    int c  = t2 % 6;   int b  = t2 / 6;
    double m = mr1[2 * c], r = mr1[2 * c + 1];
    double gg = (double)g1[c], bb = (double)be1[c];
    bool useMax = (r * gg) >= 0.0;              // selection only
    const __hip_bfloat16* src = c1 + (((size_t)b * 6 + c) * 28 + 2 * ph) * 28 + 4 * pp;
    ushort4 u0 = *(const ushort4*)src;
    ushort4 u1 = *(const ushort4*)(src + 28);
    float f0 = __bfloat162float(*(__hip_bfloat16*)&u0.x), f1 = __bfloat162float(*(__hip_bfloat16*)&u0.y);
    float f2 = __bfloat162float(*(__hip_bfloat16*)&u0.z), f3 = __bfloat162float(*(__hip_bfloat16*)&u0.w);
    float f4 = __bfloat162float(*(__hip_bfloat16*)&u1.x), f5 = __bfloat162float(*(__hip_bfloat16*)&u1.y);
    float f6 = __bfloat162float(*(__hip_bfloat16*)&u1.z), f7 = __bfloat162float(*(__hip_bfloat16*)&u1.w);
    float va = useMax ? fmaxf(fmaxf(f0, f1), fmaxf(f4, f5))
                      : fminf(fminf(f0, f1), fminf(f4, f5));
    float vb = useMax ? fmaxf(fmaxf(f2, f3), fmaxf(f6, f7))
                      : fminf(fminf(f2, f3), fminf(f6, f7));
    double qa = fq_d((((double)va - m) * r) * gg + bb);
    double qb = fq_d((((double)vb - m) * r) * gg + bb);
    qa = fmax(qa, 0.0); qb = fmax(qb, 0.0);
    ushort2 pk; pk.x = bfbits(qa); pk.y = bfbits(qb);
    *(ushort2*)&p1[((size_t)b * 6 + c) * 196 + ph * 14 + 2 * pp] = pk;
}

// ---------------- conv2 + fq + fused BN stats ----------------
// [B,6,14,14] -> [B,16,10,10]. 2 images/block, 320 thr; task = 1x10 row
// (320 tasks exactly). x,w in LDS f32 (exact), f64 acc.
__global__ __launch_bounds__(320) void kconv2(const __hip_bfloat16* __restrict__ p1,
        const float* __restrict__ qw, __hip_bfloat16* __restrict__ c2,
        double* __restrict__ st2) {
    __shared__ float sxf[2352];    // 2 x [6][14][14]
    __shared__ float swf[2400];    // [16][6][5][5]
    __shared__ double sred[16][2];
    int t = threadIdx.x;
    int b0 = blockIdx.x * 2;
    for (int i = t; i < 2352; i += 320) sxf[i] = __bfloat162float(p1[(size_t)b0 * 1176 + i]);
    for (int i = t; i < 2400; i += 320) swf[i] = qw[i];
    if (t < 32) ((double*)sred)[t] = 0.0;
    __syncthreads();
    int img = t / 160, r = t % 160;
    int co = r / 10, i0 = r % 10;
    const float* xb = &sxf[img * 1176];
    const float* wb = &swf[co * 150];
    double acc[10];
    #pragma unroll
    for (int j = 0; j < 10; ++j) acc[j] = 0.0;
    for (int ci = 0; ci < 6; ++ci) {
        #pragma unroll
        for (int u = 0; u < 5; ++u) {
            const float* xr = &xb[ci * 196 + (i0 + u) * 14];
            double xv[14];
            #pragma unroll
            for (int k = 0; k < 14; ++k) xv[k] = (double)xr[k];
            double w0 = (double)wb[ci*25+u*5],   w1 = (double)wb[ci*25+u*5+1];
            double w2 = (double)wb[ci*25+u*5+2], w3 = (double)wb[ci*25+u*5+3];
            double w4 = (double)wb[ci*25+u*5+4];
            #pragma unroll
            for (int j = 0; j < 10; ++j)
                acc[j] = fma(xv[j], w0, fma(xv[j+1], w1, fma(xv[j+2], w2,
                         fma(xv[j+3], w3, fma(xv[j+4], w4, acc[j])))));
        }
    }
    size_t base = ((size_t)(b0 + img) * 16 + co) * 100 + (size_t)i0 * 10;
    double s = 0.0, s2 = 0.0;
    #pragma unroll
    for (int j = 0; j < 10; j += 2) {
        double q0 = fq_d(acc[j]), q1 = fq_d(acc[j+1]);
        ushort2 pk; pk.x = bfbits(q0); pk.y = bfbits(q1);
        *(ushort2*)((unsigned short*)c2 + base + j) = pk;
        s += q0 + q1; s2 += q0 * q0 + q1 * q1;
    }
    atomicAdd(&sred[co][0], s);
    atomicAdd(&sred[co][1], s2);
    __syncthreads();
    if (t < 32) atomicAdd(&st2[t * 32 + (blockIdx.x & 31)], ((double*)sred)[t]);
}

// ---------------- fc1 (+fused bn2/fq/relu/pool staging, single-fq) ---------
__global__ __launch_bounds__(256) void kfc1(const __hip_bfloat16* __restrict__ c2,
        const double* __restrict__ mr2, const float* __restrict__ g2,
        const float* __restrict__ be2, const float* __restrict__ Wt,
        const float* __restrict__ qb, __hip_bfloat16* __restrict__ outb) {
    constexpr int IN = 400, OUT = 120, OUTP = 128, ROWS = 8, BT = 16;
    __shared__ double sx[BT][IN];
    __shared__ double sbn[16][4];
    int t = threadIdx.x;
    int b0 = blockIdx.x * BT;
    if (t < 16) {
        sbn[t][0] = mr2[2 * t]; sbn[t][1] = mr2[2 * t + 1];
        sbn[t][2] = (double)g2[t]; sbn[t][3] = (double)be2[t];
    }
    __syncthreads();
    for (int i = t; i < BT * IN; i += 256) {
        int r = i / IN, k = i % IN;
        int c = k / 25, rem = k % 25;
        int ph = rem / 5, pw = rem % 5;
        const __hip_bfloat16* src = c2 + (((size_t)(b0 + r) * 16 + c) * 10 + 2 * ph) * 10 + 2 * pw;
        double m = sbn[c][0], rr = sbn[c][1], gg = sbn[c][2], bb = sbn[c][3];
        float f0 = __bfloat162float(src[0]),  f1 = __bfloat162float(src[1]);
        float f2 = __bfloat162float(src[10]), f3 = __bfloat162float(src[11]);
        bool useMax = (rr * gg) >= 0.0;
        float v = useMax ? fmaxf(fmaxf(f0, f1), fmaxf(f2, f3))
                         : fminf(fminf(f0, f1), fminf(f2, f3));
        double q = fq_d((((double)v - m) * rr) * gg + bb);
        sx[r][k] = fmax(q, 0.0);
    }
    __syncthreads();
    int o = t % OUTP;
    int g = t / OUTP;
    double acc[ROWS];
    double bias = (o < OUT) ? (double)qb[o] : 0.0;
    #pragma unroll
    for (int r = 0; r < ROWS; ++r) acc[r] = bias;
    #pragma unroll 4
    for (int k = 0; k < IN; ++k) {
        double w = (double)Wt[k * OUTP + o];
        #pragma unroll
        for (int r = 0; r < ROWS; ++r)
            acc[r] = fma(sx[g * ROWS + r][k], w, acc[r]);
    }
    if (o < OUT) {
        #pragma unroll
        for (int r = 0; r < ROWS; ++r) {
            double q = fq_d(acc[r]);
            if (q < 0.0) q = 0.0;
            outb[(size_t)(b0 + g * ROWS + r) * OUT + o] = __float2bfloat16((float)q);
        }
    }
}

// ---------------- fused fc2+fc3: a1 [B,120] -> out [B,10] ----------------
// fc2 result (relu fq) kept in LDS; fc3 reads it directly.
__global__ __launch_bounds__(256) void kfc23(const __hip_bfloat16* __restrict__ a1,
        const float* __restrict__ Wt2, const float* __restrict__ qfb2,
        const float* __restrict__ Wt3, const float* __restrict__ qfb3,
        float* __restrict__ out) {
    __shared__ double sx1[16][120];
    __shared__ double s2[16][84];
    int t = threadIdx.x;
    int b0 = blockIdx.x * 16;
    for (int i = t; i < 16 * 120; i += 256) {
        int r = i / 120, k = i % 120;
        sx1[r][k] = (double)__bfloat162float(a1[(size_t)(b0 + r) * 120 + k]);
    }
    __syncthreads();
    {   // fc2: 2 groups x 8 rows x 128 output lanes
        int o = t % 128, g = t / 128;
        double acc[8];
        double bias = (o < 84) ? (double)qfb2[o] : 0.0;
        #pragma unroll
        for (int r = 0; r < 8; ++r) acc[r] = bias;
        #pragma unroll 4
        for (int k = 0; k < 120; ++k) {
            double w = (double)Wt2[k * 128 + o];
            #pragma unroll
            for (int r = 0; r < 8; ++r)
                acc[r] = fma(sx1[g * 8 + r][k], w, acc[r]);
        }
        if (o < 84) {
            #pragma unroll
            for (int r = 0; r < 8; ++r) {
                double q = fq_d(acc[r]);
                s2[g * 8 + r][o] = fmax(q, 0.0);
            }
        }
    }
    __syncthreads();
    {   // fc3: 16 rows x 16 output lanes (10 used)
        int o = t % 16, g = t / 16;
        double acc = (o < 10) ? (double)qfb3[o] : 0.0;
        #pragma unroll 4
        for (int k = 0; k < 84; ++k)
            acc = fma(s2[g][k], (double)Wt3[k * 16 + o], acc);
        if (o < 10)
            out[(size_t)(b0 + g) * 10 + o] = (float)fq_d(acc);
    }
}

// ---------------------------------------------------------------------------
extern "C" void kernel_launch(void* const* d_in, const int* in_sizes, int n_in,
                              void* d_out, int out_size, void* d_ws, size_t ws_size,
                              hipStream_t stream) {
    const float* x   = (const float*)d_in[0];
    const float* w1  = (const float*)d_in[1];
    const float* g1  = (const float*)d_in[2];
    const float* be1 = (const float*)d_in[3];
    const float* w2  = (const float*)d_in[4];
    const float* g2  = (const float*)d_in[5];
    const float* be2 = (const float*)d_in[6];
    const float* fw1 = (const float*)d_in[7];
    const float* fb1 = (const float*)d_in[8];
    const float* fw2 = (const float*)d_in[9];
    const float* fb2 = (const float*)d_in[10];
    const float* fw3 = (const float*)d_in[11];
    const float* fb3 = (const float*)d_in[12];

    char* ws = (char*)d_ws;
    double* stats1 = (double*)(ws + 0);      // [6][2][32] dbl
    double* stats2 = (double*)(ws + 3072);   // [16][2][32] dbl (ends 11264)
    double* mr1    = (double*)(ws + 11264);
    double* mr2    = (double*)(ws + 11392);
    float* qw1  = (float*)(ws + 12288);
    float* qw2  = (float*)(ws + 13312);
    float* qfb1 = (float*)(ws + 23040);
    float* qfb2 = (float*)(ws + 23552);
    float* qfb3 = (float*)(ws + 24064);
    float* Wt1  = (float*)(ws + 24576);      // 400*128
    float* Wt2  = (float*)(ws + 229376);     // 120*128
    float* Wt3  = (float*)(ws + 290816);     // 84*16
    __hip_bfloat16* c1 = (__hip_bfloat16*)(ws + 303104);      // [B,6,28,28] 77.1 MB
    __hip_bfloat16* p1 = (__hip_bfloat16*)(ws + 77373440);    // [B,6,14,14] 19.3 MB
    __hip_bfloat16* c2 = (__hip_bfloat16*)(ws + 303104);      // [B,16,10,10] (c1 dead)
    __hip_bfloat16* a1 = (__hip_bfloat16*)(ws + 303104 + 26214400); // [B,120]

    hipMemsetAsync(ws, 0, 11264, stream);

    kprep<<<(PREP_TOTAL + 255) / 256, 256, 0, stream>>>(
        w1, w2, fb1, fb2, fb3, fw1, fw2, fw3,
        qw1, qw2, qfb1, qfb2, qfb3, Wt1, Wt2, Wt3);

    // conv1 + fq + stats -> c1   (2 images/block, 1x7 tasks)
    kconv1<<<BATCH / 2, 256, 0, stream>>>(x, qw1, c1, stats1);
    kfinal<<<1, 32, 0, stream>>>(stats1, mr1, 6, (double)BATCH * 784.0);
    // bn1 + fq + relu + pool -> p1
    kpool1<<<BATCH * 6 * 14 * 7 / 256, 256, 0, stream>>>(c1, mr1, g1, be1, p1);
    // conv2 + fq + stats -> c2   (2 images/block, 1x10 tasks)
    kconv2<<<BATCH / 2, 320, 0, stream>>>(p1, qw2, c2, stats2);
    kfinal<<<1, 32, 0, stream>>>(stats2, mr2, 16, (double)BATCH * 100.0);
    // fc1 (fused bn2/pool staging, +relu) -> a1 [B,120]
    kfc1<<<BATCH / 16, 256, 0, stream>>>(c2, mr2, g2, be2, Wt1, qfb1, a1);
    // fused fc2+fc3 -> d_out [B,10] float
    kfc23<<<BATCH / 16, 256, 0, stream>>>(a1, Wt2, qfb2, Wt3, qfb3, (float*)d_out);
}

// Round 11
// 410.541 us; speedup vs baseline: 1.1253x; 1.1253x over previous
//
#include <hip/hip_runtime.h>
#include <hip/hip_bf16.h>

// ---------------------------------------------------------------------------
// QLenet forward, exact-math strategy (round-0 notes):
//   All fq() outputs are e5m2 grid values (<=3 significant bits). Products of
//   two grid values have <=6-bit mantissas; dot sums (<=400 terms, bounded
//   exponent span) are EXACT in f64 -> order-independent -> matches float64
//   numpy reference. Intermediates stored as bf16 (exact for grid values);
//   LDS tiles hold f32 (also exact), accumulation stays f64.
// Round 10 -> 11:
//   * r10's conv re-tilings REVERTED (kconv1 119->147, kconv2 150->155;
//     occupancy counter not actionable — both convs sit near the f64-FMA
//     issue floor ~8cy/wave-instr; tiling changes don't move them).
//   * fq_f: f32 integer-RNE quantizer for inputs that are exact f32
//     (weights in kprep, conv1 input staging) — same result, cheaper ops.
//   * kfc1: BT 16->8 (1024 blocks, 4/CU) — halves serial staging per block,
//     doubles resident waves; bn2 finalize folded in (reads stats2 bins).
//   * kfc23 kept from r10. Launches 9 -> 8.
// ---------------------------------------------------------------------------

#define BATCH 8192

// fq on f64: round to FP(e5m2) nearest-even, subnormal granule 2^-16,
// clip +-57344. Integer RNE on the mantissa; carry propagates into exponent.
__device__ __forceinline__ double fq_d(double x) {
    long long b = __double_as_longlong(x);
    long long ab = b & 0x7fffffffffffffffLL;
    if (ab == 0) return x;                       // +-0 preserved
    double q;
    if (ab >= 0x3F10000000000000LL) {            // |x| >= 2^-14
        long long r = b + 0x0001FFFFFFFFFFFFLL + ((b >> 50) & 1LL);
        r &= 0xFFFC000000000000LL;
        q = __longlong_as_double(r);
        q = fmin(fmax(q, -57344.0), 57344.0);
    } else {                                     // subnormal grid: 2^-16
        q = rint(x * 65536.0) * 1.52587890625e-05;
    }
    return q;
}

// fq on f32 input values (exact f32 -> same e5m2 result as the f64 path).
__device__ __forceinline__ float fq_f(float x) {
    int b = __float_as_int(x);
    int ab = b & 0x7fffffff;
    if (ab == 0) return x;
    float q;
    if (ab >= 0x38800000) {                      // |x| >= 2^-14
        int r = b + 0x000FFFFF + ((b >> 21) & 1);
        r &= 0xFFE00000;                         // sign+exp+2 mantissa bits
        q = __int_as_float(r);
        q = fminf(fmaxf(q, -57344.0f), 57344.0f);
    } else {
        q = rintf(x * 65536.0f) * 1.52587890625e-05f;
    }
    return q;
}

__device__ __forceinline__ unsigned short bfbits(double q) {
    __hip_bfloat16 h = __float2bfloat16((float)q);   // exact for grid values
    return *(unsigned short*)&h;
}

// ---------------- merged prep (all f32-path fq) ----------------
__global__ void kprep(const float* __restrict__ w1, const float* __restrict__ w2,
                      const float* __restrict__ fb1, const float* __restrict__ fb2,
                      const float* __restrict__ fb3, const float* __restrict__ fw1,
                      const float* __restrict__ fw2, const float* __restrict__ fw3,
                      float* __restrict__ qw1, float* __restrict__ qw2,
                      float* __restrict__ qfb1, float* __restrict__ qfb2,
                      float* __restrict__ qfb3, float* __restrict__ Wt1,
                      float* __restrict__ Wt2, float* __restrict__ Wt3) {
    int i = blockIdx.x * 256 + threadIdx.x;
    if (i < 150) { qw1[i] = fq_f(w1[i]); return; }
    i -= 150;
    if (i < 2400) { qw2[i] = fq_f(w2[i]); return; }
    i -= 2400;
    if (i < 120) { qfb1[i] = fq_f(fb1[i]); return; }
    i -= 120;
    if (i < 84) { qfb2[i] = fq_f(fb2[i]); return; }
    i -= 84;
    if (i < 10) { qfb3[i] = fq_f(fb3[i]); return; }
    i -= 10;
    if (i < 51200) { int k = i / 128, o = i % 128;
        Wt1[i] = (o < 120) ? fq_f(fw1[o * 400 + k]) : 0.0f; return; }
    i -= 51200;
    if (i < 15360) { int k = i / 128, o = i % 128;
        Wt2[i] = (o < 84) ? fq_f(fw2[o * 120 + k]) : 0.0f; return; }
    i -= 15360;
    if (i < 1344) { int k = i / 16, o = i % 16;
        Wt3[i] = (o < 10) ? fq_f(fw3[o * 84 + k]) : 0.0f; return; }
}
#define PREP_TOTAL (150 + 2400 + 120 + 84 + 10 + 51200 + 15360 + 1344)

// ---------------- conv1 + fq + fused BN stats (r9 version) ----------------
// [B,1,32,32] -> [B,6,28,28]. 3 images/block; task = 2x7 output tile with
// rotated-w row reuse. x tile f32 (fq_f staging), stride 33.
__global__ __launch_bounds__(256) void kconv1(const float* __restrict__ x,
        const float* __restrict__ qw, __hip_bfloat16* __restrict__ c1,
        int nimg_total, double* __restrict__ st1) {
    __shared__ float sxf[3 * 1056];   // 3 x (32 rows x 33) f32
    __shared__ double swd[152];
    __shared__ double sred[6][2];
    int t = threadIdx.x;
    int b0 = blockIdx.x * 3;
    int nimg = nimg_total - b0; if (nimg > 3) nimg = 3;
    for (int i = t; i < nimg * 1024; i += 256) {
        int img = i >> 10, idx = i & 1023;
        sxf[img * 1056 + (idx >> 5) * 33 + (idx & 31)] =
            fq_f(x[(size_t)(b0 + img) * 1024 + idx]);
    }
    if (t < 150) swd[t] = (double)qw[t];
    if (t >= 192 && t < 204) ((double*)sred)[t - 192] = 0.0;
    __syncthreads();
    int ntask = nimg * 336;           // 6 co x 14 rowpairs x 4 colchunks
    for (int task = t; task < ntask; task += 256) {
        int img = task / 336; int rr = task % 336;
        int co = rr / 56; int rem = rr % 56;
        int i0 = (rem >> 2) * 2;      // 0,2,...,26
        int j0 = (rem & 3) * 7;       // 0,7,14,21
        const double* wp = &swd[co * 25];
        double a0[7], a1[7];
        #pragma unroll
        for (int j = 0; j < 7; ++j) { a0[j] = 0.0; a1[j] = 0.0; }
        double wr[5], wq[5];
        #pragma unroll
        for (int u = 0; u < 6; ++u) {
            const float* xr = &sxf[img * 1056 + (i0 + u) * 33 + j0];
            double xv[11];
            #pragma unroll
            for (int k = 0; k < 11; ++k) xv[k] = (double)xr[k];
            if (u < 5) {
                #pragma unroll
                for (int tt = 0; tt < 5; ++tt) wr[tt] = wp[u * 5 + tt];
                #pragma unroll
                for (int j = 0; j < 7; ++j)
                    a0[j] = fma(xv[j], wr[0], fma(xv[j+1], wr[1], fma(xv[j+2], wr[2],
                            fma(xv[j+3], wr[3], fma(xv[j+4], wr[4], a0[j])))));
            }
            if (u >= 1) {
                #pragma unroll
                for (int j = 0; j < 7; ++j)
                    a1[j] = fma(xv[j], wq[0], fma(xv[j+1], wq[1], fma(xv[j+2], wq[2],
                            fma(xv[j+3], wq[3], fma(xv[j+4], wq[4], a1[j])))));
            }
            #pragma unroll
            for (int tt = 0; tt < 5; ++tt) wq[tt] = wr[tt];   // SSA rotate
        }
        size_t base = ((size_t)(b0 + img) * 6 + co) * 784 + (size_t)i0 * 28 + j0;
        double s = 0.0, s2 = 0.0;
        #pragma unroll
        for (int j = 0; j < 7; ++j) {
            double q0 = fq_d(a0[j]), q1 = fq_d(a1[j]);
            ((unsigned short*)c1)[base + j]      = bfbits(q0);
            ((unsigned short*)c1)[base + 28 + j] = bfbits(q1);
            s += q0 + q1; s2 += q0 * q0 + q1 * q1;
        }
        atomicAdd(&sred[co][0], s);
        atomicAdd(&sred[co][1], s2);
    }
    __syncthreads();
    if (t < 12) atomicAdd(&st1[t * 32 + (blockIdx.x & 31)], ((double*)sred)[t]);
}

// ---------------- finalize BN1 from 32-binned stats ----------------
__global__ void kfinal(const double* __restrict__ st, double* __restrict__ mr,
                       int C, double N) {
    int c = threadIdx.x;
    if (c < C) {
        double s = 0.0, s2 = 0.0;
        for (int b = 0; b < 32; ++b) { s += st[c * 64 + b]; s2 += st[c * 64 + 32 + b]; }
        double m = s / N;
        double v = s2 / N - m * m;
        mr[2 * c] = m;
        mr[2 * c + 1] = 1.0 / sqrt(v + 1e-5);
    }
}

// ---------------- bn1 + fq + relu + 2x2 pool (monotone single-fq) ----------
__global__ __launch_bounds__(256) void kpool1(const __hip_bfloat16* __restrict__ c1,
        const double* __restrict__ mr1, const float* __restrict__ g1,
        const float* __restrict__ be1, __hip_bfloat16* __restrict__ p1) {
    int idx = blockIdx.x * 256 + threadIdx.x;   // pair-task: B*6*14*7
    int pp = idx % 7;  int t1 = idx / 7;
    int ph = t1 % 14;  int t2 = t1 / 14;
    int c  = t2 % 6;   int b  = t2 / 6;
    double m = mr1[2 * c], r = mr1[2 * c + 1];
    double gg = (double)g1[c], bb = (double)be1[c];
    bool useMax = (r * gg) >= 0.0;              // selection only
    const __hip_bfloat16* src = c1 + (((size_t)b * 6 + c) * 28 + 2 * ph) * 28 + 4 * pp;
    ushort4 u0 = *(const ushort4*)src;
    ushort4 u1 = *(const ushort4*)(src + 28);
    float f0 = __bfloat162float(*(__hip_bfloat16*)&u0.x), f1 = __bfloat162float(*(__hip_bfloat16*)&u0.y);
    float f2 = __bfloat162float(*(__hip_bfloat16*)&u0.z), f3 = __bfloat162float(*(__hip_bfloat16*)&u0.w);
    float f4 = __bfloat162float(*(__hip_bfloat16*)&u1.x), f5 = __bfloat162float(*(__hip_bfloat16*)&u1.y);
    float f6 = __bfloat162float(*(__hip_bfloat16*)&u1.z), f7 = __bfloat162float(*(__hip_bfloat16*)&u1.w);
    float va = useMax ? fmaxf(fmaxf(f0, f1), fmaxf(f4, f5))
                      : fminf(fminf(f0, f1), fminf(f4, f5));
    float vb = useMax ? fmaxf(fmaxf(f2, f3), fmaxf(f6, f7))
                      : fminf(fminf(f2, f3), fminf(f6, f7));
    double qa = fq_d((((double)va - m) * r) * gg + bb);
    double qb = fq_d((((double)vb - m) * r) * gg + bb);
    qa = fmax(qa, 0.0); qb = fmax(qb, 0.0);
    ushort2 pk; pk.x = bfbits(qa); pk.y = bfbits(qb);
    *(ushort2*)&p1[((size_t)b * 6 + c) * 196 + ph * 14 + 2 * pp] = pk;
}

// ---------------- conv2 + fq + fused BN stats (r9 version) ----------------
// [B,6,14,14] -> [B,16,10,10]. 4 images/block, 320 thr; task = 2x10 row-pair
// tile with rotated-w row reuse. x,w in LDS f32 (exact), f64 acc.
__global__ __launch_bounds__(320) void kconv2(const __hip_bfloat16* __restrict__ p1,
        const float* __restrict__ qw, __hip_bfloat16* __restrict__ c2,
        double* __restrict__ st2) {
    __shared__ float sxf[4704];    // 4 x [6][14][14]
    __shared__ float swf[2400];    // [16][6][5][5]
    __shared__ double sred[16][2];
    int t = threadIdx.x;
    int b0 = blockIdx.x * 4;
    for (int i = t; i < 4704; i += 320) sxf[i] = __bfloat162float(p1[(size_t)b0 * 1176 + i]);
    for (int i = t; i < 2400; i += 320) swf[i] = qw[i];
    if (t < 32) ((double*)sred)[t] = 0.0;
    __syncthreads();
    int img = t / 80, r = t % 80;
    int co = r / 5, i0 = (r % 5) * 2;
    const float* xb = &sxf[img * 1176];
    const float* wb = &swf[co * 150];
    double a0[10], a1[10];
    #pragma unroll
    for (int j = 0; j < 10; ++j) { a0[j] = 0.0; a1[j] = 0.0; }
    double wr[5], wq[5];
    for (int ci = 0; ci < 6; ++ci) {
        #pragma unroll
        for (int u = 0; u < 6; ++u) {
            const float* xr = &xb[ci * 196 + (i0 + u) * 14];
            double xv[14];
            #pragma unroll
            for (int k = 0; k < 14; ++k) xv[k] = (double)xr[k];
            if (u < 5) {
                #pragma unroll
                for (int tt = 0; tt < 5; ++tt) wr[tt] = (double)wb[ci * 25 + u * 5 + tt];
                #pragma unroll
                for (int j = 0; j < 10; ++j)
                    a0[j] = fma(xv[j], wr[0], fma(xv[j+1], wr[1], fma(xv[j+2], wr[2],
                            fma(xv[j+3], wr[3], fma(xv[j+4], wr[4], a0[j])))));
            }
            if (u >= 1) {
                #pragma unroll
                for (int j = 0; j < 10; ++j)
                    a1[j] = fma(xv[j], wq[0], fma(xv[j+1], wq[1], fma(xv[j+2], wq[2],
                            fma(xv[j+3], wq[3], fma(xv[j+4], wq[4], a1[j])))));
            }
            #pragma unroll
            for (int tt = 0; tt < 5; ++tt) wq[tt] = wr[tt];   // SSA rotate
        }
    }
    size_t base = ((size_t)(b0 + img) * 16 + co) * 100 + (size_t)i0 * 10;
    double s = 0.0, s2 = 0.0;
    #pragma unroll
    for (int j = 0; j < 10; ++j) {
        double q0 = fq_d(a0[j]), q1 = fq_d(a1[j]);
        ((unsigned short*)c2)[base + j]      = bfbits(q0);
        ((unsigned short*)c2)[base + 10 + j] = bfbits(q1);
        s += q0 + q1; s2 += q0 * q0 + q1 * q1;
    }
    atomicAdd(&sred[co][0], s);
    atomicAdd(&sred[co][1], s2);
    __syncthreads();
    if (t < 32) atomicAdd(&st2[t * 32 + (blockIdx.x & 31)], ((double*)sred)[t]);
}

// ---------------- fc1: fused bn2-finalize + bn2/fq/relu/pool staging -------
// BT=8 (1024 blocks, 4/CU): halved serial staging, doubled resident waves.
__global__ __launch_bounds__(256) void kfc1(const __hip_bfloat16* __restrict__ c2,
        const double* __restrict__ st2, const float* __restrict__ g2,
        const float* __restrict__ be2, const float* __restrict__ Wt,
        const float* __restrict__ qb, __hip_bfloat16* __restrict__ outb) {
    constexpr int IN = 400, OUT = 120, OUTP = 128, ROWS = 4, BT = 8;
    __shared__ double sx[BT][IN];
    __shared__ double sbn[16][4];
    int t = threadIdx.x;
    int b0 = blockIdx.x * BT;
    if (t < 16) {                       // inline bn2 finalize from stat bins
        double s = 0.0, s2 = 0.0;
        for (int b = 0; b < 32; ++b) { s += st2[t * 64 + b]; s2 += st2[t * 64 + 32 + b]; }
        double m = s / (819200.0);      // 8192*100
        double v = s2 / (819200.0) - m * m;
        sbn[t][0] = m; sbn[t][1] = 1.0 / sqrt(v + 1e-5);
        sbn[t][2] = (double)g2[t]; sbn[t][3] = (double)be2[t];
    }
    __syncthreads();
    for (int i = t; i < BT * IN; i += 256) {
        int r = i / IN, k = i % IN;
        int c = k / 25, rem = k % 25;
        int ph = rem / 5, pw = rem % 5;
        const __hip_bfloat16* src = c2 + (((size_t)(b0 + r) * 16 + c) * 10 + 2 * ph) * 10 + 2 * pw;
        double m = sbn[c][0], rr = sbn[c][1], gg = sbn[c][2], bb = sbn[c][3];
        float f0 = __bfloat162float(src[0]),  f1 = __bfloat162float(src[1]);
        float f2 = __bfloat162float(src[10]), f3 = __bfloat162float(src[11]);
        bool useMax = (rr * gg) >= 0.0;
        float v = useMax ? fmaxf(fmaxf(f0, f1), fmaxf(f2, f3))
                         : fminf(fminf(f0, f1), fminf(f2, f3));
        double q = fq_d((((double)v - m) * rr) * gg + bb);
        sx[r][k] = fmax(q, 0.0);
    }
    __syncthreads();
    int o = t % OUTP;
    int g = t / OUTP;
    double acc[ROWS];
    double bias = (o < OUT) ? (double)qb[o] : 0.0;
    #pragma unroll
    for (int r = 0; r < ROWS; ++r) acc[r] = bias;
    #pragma unroll 4
    for (int k = 0; k < IN; ++k) {
        double w = (double)Wt[k * OUTP + o];   // coalesced, L2-resident
        #pragma unroll
        for (int r = 0; r < ROWS; ++r)
            acc[r] = fma(sx[g * ROWS + r][k], w, acc[r]);
    }
    if (o < OUT) {
        #pragma unroll
        for (int r = 0; r < ROWS; ++r) {
            double q = fq_d(acc[r]);
            if (q < 0.0) q = 0.0;
            outb[(size_t)(b0 + g * ROWS + r) * OUT + o] = __float2bfloat16((float)q);
        }
    }
}

// ---------------- fused fc2+fc3: a1 [B,120] -> out [B,10] ----------------
__global__ __launch_bounds__(256) void kfc23(const __hip_bfloat16* __restrict__ a1,
        const float* __restrict__ Wt2, const float* __restrict__ qfb2,
        const float* __restrict__ Wt3, const float* __restrict__ qfb3,
        float* __restrict__ out) {
    __shared__ double sx1[16][120];
    __shared__ double s2[16][84];
    int t = threadIdx.x;
    int b0 = blockIdx.x * 16;
    for (int i = t; i < 16 * 120; i += 256) {
        int r = i / 120, k = i % 120;
        sx1[r][k] = (double)__bfloat162float(a1[(size_t)(b0 + r) * 120 + k]);
    }
    __syncthreads();
    {   // fc2: 2 groups x 8 rows x 128 output lanes
        int o = t % 128, g = t / 128;
        double acc[8];
        double bias = (o < 84) ? (double)qfb2[o] : 0.0;
        #pragma unroll
        for (int r = 0; r < 8; ++r) acc[r] = bias;
        #pragma unroll 4
        for (int k = 0; k < 120; ++k) {
            double w = (double)Wt2[k * 128 + o];
            #pragma unroll
            for (int r = 0; r < 8; ++r)
                acc[r] = fma(sx1[g * 8 + r][k], w, acc[r]);
        }
        if (o < 84) {
            #pragma unroll
            for (int r = 0; r < 8; ++r) {
                double q = fq_d(acc[r]);
                s2[g * 8 + r][o] = fmax(q, 0.0);
            }
        }
    }
    __syncthreads();
    {   // fc3: 16 rows x 16 output lanes (10 used)
        int o = t % 16, g = t / 16;
        double acc = (o < 10) ? (double)qfb3[o] : 0.0;
        #pragma unroll 4
        for (int k = 0; k < 84; ++k)
            acc = fma(s2[g][k], (double)Wt3[k * 16 + o], acc);
        if (o < 10)
            out[(size_t)(b0 + g) * 10 + o] = (float)fq_d(acc);
    }
}

// ---------------------------------------------------------------------------
extern "C" void kernel_launch(void* const* d_in, const int* in_sizes, int n_in,
                              void* d_out, int out_size, void* d_ws, size_t ws_size,
                              hipStream_t stream) {
    const float* x   = (const float*)d_in[0];
    const float* w1  = (const float*)d_in[1];
    const float* g1  = (const float*)d_in[2];
    const float* be1 = (const float*)d_in[3];
    const float* w2  = (const float*)d_in[4];
    const float* g2  = (const float*)d_in[5];
    const float* be2 = (const float*)d_in[6];
    const float* fw1 = (const float*)d_in[7];
    const float* fb1 = (const float*)d_in[8];
    const float* fw2 = (const float*)d_in[9];
    const float* fb2 = (const float*)d_in[10];
    const float* fw3 = (const float*)d_in[11];
    const float* fb3 = (const float*)d_in[12];

    char* ws = (char*)d_ws;
    double* stats1 = (double*)(ws + 0);      // [6][2][32] dbl
    double* stats2 = (double*)(ws + 3072);   // [16][2][32] dbl (ends 11264)
    double* mr1    = (double*)(ws + 11264);  // 12 dbl
    float* qw1  = (float*)(ws + 12288);
    float* qw2  = (float*)(ws + 13312);
    float* qfb1 = (float*)(ws + 23040);
    float* qfb2 = (float*)(ws + 23552);
    float* qfb3 = (float*)(ws + 24064);
    float* Wt1  = (float*)(ws + 24576);      // 400*128
    float* Wt2  = (float*)(ws + 229376);     // 120*128
    float* Wt3  = (float*)(ws + 290816);     // 84*16
    __hip_bfloat16* c1 = (__hip_bfloat16*)(ws + 303104);      // [B,6,28,28] 77.1 MB
    __hip_bfloat16* p1 = (__hip_bfloat16*)(ws + 77373440);    // [B,6,14,14] 19.3 MB
    __hip_bfloat16* c2 = (__hip_bfloat16*)(ws + 303104);      // [B,16,10,10] (c1 dead)
    __hip_bfloat16* a1 = (__hip_bfloat16*)(ws + 303104 + 26214400); // [B,120]

    hipMemsetAsync(ws, 0, 11264, stream);

    kprep<<<(PREP_TOTAL + 255) / 256, 256, 0, stream>>>(
        w1, w2, fb1, fb2, fb3, fw1, fw2, fw3,
        qw1, qw2, qfb1, qfb2, qfb3, Wt1, Wt2, Wt3);

    // conv1 + fq + stats -> c1   (3 images/block, 2x7 tiles)
    kconv1<<<(BATCH + 2) / 3, 256, 0, stream>>>(x, qw1, c1, BATCH, stats1);
    kfinal<<<1, 32, 0, stream>>>(stats1, mr1, 6, (double)BATCH * 784.0);
    // bn1 + fq + relu + pool -> p1
    kpool1<<<BATCH * 6 * 14 * 7 / 256, 256, 0, stream>>>(c1, mr1, g1, be1, p1);
    // conv2 + fq + stats -> c2   (4 images/block, 2x10 tiles)
    kconv2<<<BATCH / 4, 320, 0, stream>>>(p1, qw2, c2, stats2);
    // fc1 (inline bn2 finalize + fused pool staging, +relu) -> a1 [B,120]
    kfc1<<<BATCH / 8, 256, 0, stream>>>(c2, stats2, g2, be2, Wt1, qfb1, a1);
    // fused fc2+fc3 -> d_out [B,10] float
    kfc23<<<BATCH / 16, 256, 0, stream>>>(a1, Wt2, qfb2, Wt3, qfb3, (float*)d_out);
}